// Round 3
// baseline (31767.184 us; speedup 1.0000x reference)
//
#include <hip/hip_runtime.h>
#include <math.h>
#include <cstddef>
#include <cstdint>

#define B_ 8
#define S_ 4096
#define D_ 256

// ---------------------------------------------------------------------------
// GEMM: C[M,256] = A[M,256] @ W[256,256] + bias   (fp32)
// Tile 64(M) x 256(N), K chunked by 32. 256 threads = (tx=32) x (ty=8).
// 8x8 micro-tile per thread; thread's 8 N-cols are tx*4..+3 and 128+tx*4..+3
// (two float4 groups 128 apart -> B-side ds_read_b128 covers 512 contiguous
// bytes across the 32 lanes = all 32 banks, conflict-free).
// A staged transposed [k][m] -> reads are ty-broadcast (free).
// ---------------------------------------------------------------------------
__global__ __launch_bounds__(256, 2) void gemm_bias_kernel(
    const float* __restrict__ A, const float* __restrict__ W,
    const float* __restrict__ bias, float* __restrict__ C) {
  __shared__ __align__(16) float sA[32 * 68];   // A^T chunk [k][m]
  __shared__ __align__(16) float sW[32 * 260];  // W chunk [k][n]
  const int t  = threadIdx.x;
  const int tx = t & 31;
  const int ty = t >> 5;
  const size_t m0 = (size_t)blockIdx.x * 64;

  float acc[8][8] = {};

  for (int kc = 0; kc < 8; ++kc) {
    const int k0 = kc << 5;
    __syncthreads();
#pragma unroll
    for (int l = 0; l < 2; ++l) {
      const int idx = t + (l << 8);
      const int r = idx >> 3, cf = (idx & 7) << 2;
      const float4 a4 = *(const float4*)(A + (m0 + r) * 256 + k0 + cf);
      sA[(cf + 0) * 68 + r] = a4.x;
      sA[(cf + 1) * 68 + r] = a4.y;
      sA[(cf + 2) * 68 + r] = a4.z;
      sA[(cf + 3) * 68 + r] = a4.w;
    }
#pragma unroll
    for (int l = 0; l < 8; ++l) {
      const int idx = t + (l << 8);
      const int kr = idx >> 6, nc = (idx & 63) << 2;
      *(float4*)&sW[kr * 260 + nc] =
          *(const float4*)(W + (size_t)(k0 + kr) * 256 + nc);
    }
    __syncthreads();
#pragma unroll
    for (int kk = 0; kk < 32; ++kk) {
      const float4 a0 = *(const float4*)&sA[kk * 68 + (ty << 3)];
      const float4 a1 = *(const float4*)&sA[kk * 68 + (ty << 3) + 4];
      const float4 b0 = *(const float4*)&sW[kk * 260 + (tx << 2)];
      const float4 b1 = *(const float4*)&sW[kk * 260 + 128 + (tx << 2)];
      const float av[8] = {a0.x, a0.y, a0.z, a0.w, a1.x, a1.y, a1.z, a1.w};
      const float bv[8] = {b0.x, b0.y, b0.z, b0.w, b1.x, b1.y, b1.z, b1.w};
#pragma unroll
      for (int i = 0; i < 8; ++i)
#pragma unroll
        for (int c = 0; c < 8; ++c) acc[i][c] += av[i] * bv[c];
    }
  }

  const float4 bb0 = *(const float4*)(bias + (tx << 2));
  const float4 bb1 = *(const float4*)(bias + 128 + (tx << 2));
#pragma unroll
  for (int i = 0; i < 8; ++i) {
    float4 o0, o1;
    o0.x = acc[i][0] + bb0.x; o0.y = acc[i][1] + bb0.y;
    o0.z = acc[i][2] + bb0.z; o0.w = acc[i][3] + bb0.w;
    o1.x = acc[i][4] + bb1.x; o1.y = acc[i][5] + bb1.y;
    o1.z = acc[i][6] + bb1.z; o1.w = acc[i][7] + bb1.w;
    float* cp = C + (m0 + (ty << 3) + i) * 256;
    *(float4*)(cp + (tx << 2)) = o0;
    *(float4*)(cp + 128 + (tx << 2)) = o1;
  }
}

// ---------------------------------------------------------------------------
// Flash attention, fp32.  Grid (S/64, B), 256 threads = (tx=32) x (ty=8).
// BQ=64 q-rows; K/V streamed in 256-col tiles (16 outer iters).
// 8x8 micro-tile; thread's 8 cols are tx*4..+3 and 128+tx*4..+3 in both the
// scores phase (j-cols) and the PV phase (d-cols) -> all B-side b128 reads
// are 512B-contiguous across lanes = conflict-free. A-side reads broadcast.
// Online softmax in registers (xor-shuffle over tx lane bits).
// LDS = (32*68 + 32*260)*4 = 42 KB, phase-aliased (Qt|pT, Kt|V).
// ---------------------------------------------------------------------------
__global__ __launch_bounds__(256, 2) void flash_attn_kernel(
    const float* __restrict__ q, const float* __restrict__ k,
    const float* __restrict__ v, float* __restrict__ ctx) {
  __shared__ __align__(16) float sA[32 * 68];   // Q^T chunk | pT chunk
  __shared__ __align__(16) float sB[32 * 260];  // K^T chunk | V chunk
  const int t  = threadIdx.x;
  const int tx = t & 31;
  const int ty = t >> 5;
  const int q0 = blockIdx.x * 64;
  const size_t base = (size_t)blockIdx.y * S_ * D_;

  float acc[8][8] = {};   // rows 8ty+i; d-cols {tx*4+c, 128+tx*4+c}
  float m_i[8], l_i[8];
#pragma unroll
  for (int i = 0; i < 8; ++i) { m_i[i] = -INFINITY; l_i[i] = 0.f; }

  for (int jt = 0; jt < 16; ++jt) {
    const int j0 = jt << 8;
    float s[8][8] = {};  // rows 8ty+i; j-cols {tx*4+c, 128+tx*4+c}

    // ---- scores: S = (Q/16) @ K^T, D chunked by 32 ----
    for (int dc = 0; dc < 8; ++dc) {
      const int d0 = dc << 5;
      __syncthreads();
#pragma unroll
      for (int l = 0; l < 2; ++l) {
        const int idx = t + (l << 8);
        const int r = idx >> 3, cf = (idx & 7) << 2;
        const float4 qv =
            *(const float4*)(q + base + (size_t)(q0 + r) * D_ + d0 + cf);
        sA[(cf + 0) * 68 + r] = qv.x * 0.0625f;
        sA[(cf + 1) * 68 + r] = qv.y * 0.0625f;
        sA[(cf + 2) * 68 + r] = qv.z * 0.0625f;
        sA[(cf + 3) * 68 + r] = qv.w * 0.0625f;
      }
#pragma unroll
      for (int l = 0; l < 8; ++l) {
        const int idx = t + (l << 8);
        const int j = idx >> 3, cf = (idx & 7) << 2;
        const float4 kv =
            *(const float4*)(k + base + (size_t)(j0 + j) * D_ + d0 + cf);
        sB[(cf + 0) * 260 + j] = kv.x;
        sB[(cf + 1) * 260 + j] = kv.y;
        sB[(cf + 2) * 260 + j] = kv.z;
        sB[(cf + 3) * 260 + j] = kv.w;
      }
      __syncthreads();
#pragma unroll
      for (int dk = 0; dk < 32; ++dk) {
        const float4 a0 = *(const float4*)&sA[dk * 68 + (ty << 3)];
        const float4 a1 = *(const float4*)&sA[dk * 68 + (ty << 3) + 4];
        const float4 b0 = *(const float4*)&sB[dk * 260 + (tx << 2)];
        const float4 b1 = *(const float4*)&sB[dk * 260 + 128 + (tx << 2)];
        const float av[8] = {a0.x, a0.y, a0.z, a0.w, a1.x, a1.y, a1.z, a1.w};
        const float bv[8] = {b0.x, b0.y, b0.z, b0.w, b1.x, b1.y, b1.z, b1.w};
#pragma unroll
        for (int i = 0; i < 8; ++i)
#pragma unroll
          for (int c = 0; c < 8; ++c) s[i][c] += av[i] * bv[c];
      }
    }

    // ---- online softmax, fully in registers (rows live on 32 tx lanes) ----
#pragma unroll
    for (int i = 0; i < 8; ++i) {
      float mx = s[i][0];
#pragma unroll
      for (int c = 1; c < 8; ++c) mx = fmaxf(mx, s[i][c]);
#pragma unroll
      for (int off = 1; off <= 16; off <<= 1)
        mx = fmaxf(mx, __shfl_xor(mx, off, 64));
      const float mnew = fmaxf(m_i[i], mx);
      const float alpha = __expf(m_i[i] - mnew);
      m_i[i] = mnew;
      float sum = 0.f;
#pragma unroll
      for (int c = 0; c < 8; ++c) {
        s[i][c] = __expf(s[i][c] - mnew);
        sum += s[i][c];
      }
#pragma unroll
      for (int off = 1; off <= 16; off <<= 1)
        sum += __shfl_xor(sum, off, 64);
      l_i[i] = l_i[i] * alpha + sum;
#pragma unroll
      for (int c = 0; c < 8; ++c) acc[i][c] *= alpha;
    }

    // ---- PV: ctx += P @ V, j in 8 chunks of 32 ----
    for (int sj = 0; sj < 8; ++sj) {
      __syncthreads();
      // write P^T chunk [jl][qrow]: chunk sj<4 comes from cols 0-3
      // (j = tx*4+c), sj>=4 from cols 4-7 (j = 128+tx*4+c-4).
      if ((tx >> 3) == (sj & 3)) {
        const int cb = (sj >> 2) << 2;
#pragma unroll
        for (int cc = 0; cc < 4; ++cc) {
          const int jl = ((tx & 7) << 2) + cc;
          float4 p0, p1;
          p0.x = s[0][cb + cc]; p0.y = s[1][cb + cc];
          p0.z = s[2][cb + cc]; p0.w = s[3][cb + cc];
          p1.x = s[4][cb + cc]; p1.y = s[5][cb + cc];
          p1.z = s[6][cb + cc]; p1.w = s[7][cb + cc];
          *(float4*)&sA[jl * 68 + (ty << 3)]     = p0;
          *(float4*)&sA[jl * 68 + (ty << 3) + 4] = p1;
        }
      }
      // stage V chunk [32 j][256 d], natural layout
#pragma unroll
      for (int l = 0; l < 8; ++l) {
        const int idx = t + (l << 8);
        const int jr = idx >> 6, nc = (idx & 63) << 2;
        *(float4*)&sB[jr * 260 + nc] = *(const float4*)(
            v + base + (size_t)(j0 + (sj << 5) + jr) * D_ + nc);
      }
      __syncthreads();
#pragma unroll
      for (int jj = 0; jj < 32; ++jj) {
        const float4 p0 = *(const float4*)&sA[jj * 68 + (ty << 3)];
        const float4 p1 = *(const float4*)&sA[jj * 68 + (ty << 3) + 4];
        const float4 v0 = *(const float4*)&sB[jj * 260 + (tx << 2)];
        const float4 v1 = *(const float4*)&sB[jj * 260 + 128 + (tx << 2)];
        const float pv[8] = {p0.x, p0.y, p0.z, p0.w, p1.x, p1.y, p1.z, p1.w};
        const float vv[8] = {v0.x, v0.y, v0.z, v0.w, v1.x, v1.y, v1.z, v1.w};
#pragma unroll
        for (int i = 0; i < 8; ++i)
#pragma unroll
          for (int c = 0; c < 8; ++c) acc[i][c] += pv[i] * vv[c];
      }
    }
  }

  // ---- finalize: divide by l, store ----
#pragma unroll
  for (int i = 0; i < 8; ++i) {
    const float linv = 1.0f / l_i[i];
    float4 o0, o1;
    o0.x = acc[i][0] * linv; o0.y = acc[i][1] * linv;
    o0.z = acc[i][2] * linv; o0.w = acc[i][3] * linv;
    o1.x = acc[i][4] * linv; o1.y = acc[i][5] * linv;
    o1.z = acc[i][6] * linv; o1.w = acc[i][7] * linv;
    float* cp = ctx + base + (size_t)(q0 + (ty << 3) + i) * D_;
    *(float4*)(cp + (tx << 2)) = o0;
    *(float4*)(cp + 128 + (tx << 2)) = o1;
  }
}

// ---------------------------------------------------------------------------
// w[row] = dot(logits[row,:], cv)   — one wave per row, 4 rows per block
// ---------------------------------------------------------------------------
__global__ __launch_bounds__(256) void wdot_kernel(
    const float* __restrict__ logits, const float* __restrict__ cv,
    float* __restrict__ w) {
  const int t    = threadIdx.x;
  const int wave = t >> 6, lane = t & 63;
  const size_t row = (size_t)blockIdx.x * 4 + wave;
  const float4 l4 = *(const float4*)(logits + row * 256 + (lane << 2));
  const float4 c4 = *(const float4*)(cv + (lane << 2));
  float p = l4.x * c4.x + l4.y * c4.y + l4.z * c4.z + l4.w * c4.w;
#pragma unroll
  for (int off = 32; off > 0; off >>= 1) p += __shfl_down(p, off, 64);
  if (lane == 0) w[row] = p;
}

// ---------------------------------------------------------------------------
// softmax over the sequence dim per batch (in place on w) — one block per b
// ---------------------------------------------------------------------------
__global__ __launch_bounds__(256) void seq_softmax_kernel(float* __restrict__ w) {
  __shared__ float red[4];
  const int b = blockIdx.x, t = threadIdx.x;
  const int wave = t >> 6, lane = t & 63;
  float* wb = w + (size_t)b * S_;
  float vals[16];
  float mx = -INFINITY;
#pragma unroll
  for (int i = 0; i < 16; ++i) {
    vals[i] = wb[t + (i << 8)];
    mx = fmaxf(mx, vals[i]);
  }
#pragma unroll
  for (int off = 32; off > 0; off >>= 1) mx = fmaxf(mx, __shfl_xor(mx, off, 64));
  if (lane == 0) red[wave] = mx;
  __syncthreads();
  const float M = fmaxf(fmaxf(red[0], red[1]), fmaxf(red[2], red[3]));
  float sum = 0.f;
#pragma unroll
  for (int i = 0; i < 16; ++i) {
    vals[i] = __expf(vals[i] - M);
    sum += vals[i];
  }
#pragma unroll
  for (int off = 32; off > 0; off >>= 1) sum += __shfl_xor(sum, off, 64);
  __syncthreads();
  if (lane == 0) red[wave] = sum;
  __syncthreads();
  const float inv = 1.0f / (red[0] + red[1] + red[2] + red[3]);
#pragma unroll
  for (int i = 0; i < 16; ++i) wb[t + (i << 8)] = vals[i] * inv;
}

// ---------------------------------------------------------------------------
// out[b,s,:] *= nw[b,s]   (in place on d_out, float4 per thread)
// ---------------------------------------------------------------------------
__global__ __launch_bounds__(256) void scale_kernel(
    float* __restrict__ out, const float* __restrict__ nw) {
  const size_t g = (size_t)blockIdx.x * 256 + threadIdx.x;  // float4 index
  float4* o4 = (float4*)out;
  float4 vv = o4[g];
  const float sc = nw[g >> 6];
  vv.x *= sc; vv.y *= sc; vv.z *= sc; vv.w *= sc;
  o4[g] = vv;
}

// ---------------------------------------------------------------------------
extern "C" void kernel_launch(void* const* d_in, const int* in_sizes, int n_in,
                              void* d_out, int out_size, void* d_ws, size_t ws_size,
                              hipStream_t stream) {
  const float* x  = (const float*)d_in[0];
  const float* Wq = (const float*)d_in[1];
  const float* bq = (const float*)d_in[2];
  const float* Wk = (const float*)d_in[3];
  const float* bk = (const float*)d_in[4];
  const float* Wv = (const float*)d_in[5];
  const float* bv = (const float*)d_in[6];
  const float* Wo = (const float*)d_in[7];
  const float* bo = (const float*)d_in[8];
  const float* cv = (const float*)d_in[9];
  float* out = (float*)d_out;

  const size_t N = (size_t)B_ * S_ * D_;  // 8,388,608
  float* q   = (float*)d_ws;
  float* k   = q + N;
  float* v   = k + N;
  float* ctx = v + N;
  float* w   = ctx + N;  // B*S floats

  gemm_bias_kernel<<<512, 256, 0, stream>>>(x, Wq, bq, q);
  gemm_bias_kernel<<<512, 256, 0, stream>>>(x, Wk, bk, k);
  gemm_bias_kernel<<<512, 256, 0, stream>>>(x, Wv, bv, v);
  flash_attn_kernel<<<dim3(64, 8), 256, 0, stream>>>(q, k, v, ctx);
  gemm_bias_kernel<<<512, 256, 0, stream>>>(ctx, Wo, bo, out);
  wdot_kernel<<<8192, 256, 0, stream>>>(out, cv, w);
  seq_softmax_kernel<<<8, 256, 0, stream>>>(w);
  scale_kernel<<<8192, 256, 0, stream>>>(out, w);
}

// Round 4
// 2816.861 us; speedup vs baseline: 11.2775x; 11.2775x over previous
//
#include <hip/hip_runtime.h>
#include <math.h>
#include <cstddef>
#include <cstdint>

#define B_ 8
#define S_ 4096
#define D_ 256

// ---------------------------------------------------------------------------
// GEMM: C[M,256] = A[M,256] @ W[256,256] + bias   (fp32)
// Tile 64(M) x 256(N), K chunked by 32. 256 threads = (tx=32) x (ty=8).
// 8x8 micro-tile; thread's 8 N-cols are {tx*4..+3, 128+tx*4..+3} -> B-side
// ds_read_b128 spans 512 contiguous bytes across the 32 tx lanes (all banks,
// conflict-free; lanes 32-63 are 2-way broadcast = free).
// A staged transposed [k][m] -> reads are ty-broadcast (free).
// ---------------------------------------------------------------------------
__global__ __launch_bounds__(256, 2) void gemm_bias_kernel(
    const float* __restrict__ A, const float* __restrict__ W,
    const float* __restrict__ bias, float* __restrict__ C) {
  __shared__ __align__(16) float sA[32 * 68];   // A^T chunk [k][m]
  __shared__ __align__(16) float sW[32 * 260];  // W chunk [k][n]
  const int t  = threadIdx.x;
  const int tx = t & 31;
  const int ty = t >> 5;
  const size_t m0 = (size_t)blockIdx.x * 64;

  float acc[8][8] = {};

  for (int kc = 0; kc < 8; ++kc) {
    const int k0 = kc << 5;
    __syncthreads();
#pragma unroll
    for (int l = 0; l < 2; ++l) {
      const int idx = t + (l << 8);
      const int r = idx >> 3, cf = (idx & 7) << 2;
      const float4 a4 = *(const float4*)(A + (m0 + r) * 256 + k0 + cf);
      sA[(cf + 0) * 68 + r] = a4.x;
      sA[(cf + 1) * 68 + r] = a4.y;
      sA[(cf + 2) * 68 + r] = a4.z;
      sA[(cf + 3) * 68 + r] = a4.w;
    }
#pragma unroll
    for (int l = 0; l < 8; ++l) {
      const int idx = t + (l << 8);
      const int kr = idx >> 6, nc = (idx & 63) << 2;
      *(float4*)&sW[kr * 260 + nc] =
          *(const float4*)(W + (size_t)(k0 + kr) * 256 + nc);
    }
    __syncthreads();
#pragma unroll
    for (int kk = 0; kk < 32; ++kk) {
      const float4 a0 = *(const float4*)&sA[kk * 68 + (ty << 3)];
      const float4 a1 = *(const float4*)&sA[kk * 68 + (ty << 3) + 4];
      const float4 b0 = *(const float4*)&sW[kk * 260 + (tx << 2)];
      const float4 b1 = *(const float4*)&sW[kk * 260 + 128 + (tx << 2)];
      const float av[8] = {a0.x, a0.y, a0.z, a0.w, a1.x, a1.y, a1.z, a1.w};
      const float bv[8] = {b0.x, b0.y, b0.z, b0.w, b1.x, b1.y, b1.z, b1.w};
#pragma unroll
      for (int i = 0; i < 8; ++i)
#pragma unroll
        for (int c = 0; c < 8; ++c) acc[i][c] += av[i] * bv[c];
    }
  }

  const float4 bb0 = *(const float4*)(bias + (tx << 2));
  const float4 bb1 = *(const float4*)(bias + 128 + (tx << 2));
#pragma unroll
  for (int i = 0; i < 8; ++i) {
    float4 o0, o1;
    o0.x = acc[i][0] + bb0.x; o0.y = acc[i][1] + bb0.y;
    o0.z = acc[i][2] + bb0.z; o0.w = acc[i][3] + bb0.w;
    o1.x = acc[i][4] + bb1.x; o1.y = acc[i][5] + bb1.y;
    o1.z = acc[i][6] + bb1.z; o1.w = acc[i][7] + bb1.w;
    float* cp = C + (m0 + (ty << 3) + i) * 256;
    *(float4*)(cp + (tx << 2)) = o0;
    *(float4*)(cp + 128 + (tx << 2)) = o1;
  }
}

// ---------------------------------------------------------------------------
// Flash attention, fp32.  Grid (S/64, B), 256 threads = (tx=32) x (ty=8).
// Same split-column 8x8 micro-tile as the GEMM in both phases.
// PV chunk loop: outer `half` loop is FORCE-UNROLLED (2 iters) so the score
// register-array column base (cb = half*4) is a compile-time constant —
// dynamic indexing into s[][] caused full scratch-spill in round 3
// (WRITE_SIZE 135 GB). Inner sjl loop only feeds LDS addresses/predicates.
// LDS = (32*68 + 32*260)*4 = 42 KB, phase-aliased (Qt|pT, Kt|V).
// ---------------------------------------------------------------------------
__global__ __launch_bounds__(256, 2) void flash_attn_kernel(
    const float* __restrict__ q, const float* __restrict__ k,
    const float* __restrict__ v, float* __restrict__ ctx) {
  __shared__ __align__(16) float sA[32 * 68];   // Q^T chunk | pT chunk
  __shared__ __align__(16) float sB[32 * 260];  // K^T chunk | V chunk
  const int t  = threadIdx.x;
  const int tx = t & 31;
  const int ty = t >> 5;
  const int q0 = blockIdx.x * 64;
  const size_t base = (size_t)blockIdx.y * S_ * D_;

  float acc[8][8] = {};   // rows 8ty+i; d-cols {tx*4+c, 128+tx*4+c-4}
  float m_i[8], l_i[8];
#pragma unroll
  for (int i = 0; i < 8; ++i) { m_i[i] = -INFINITY; l_i[i] = 0.f; }

  for (int jt = 0; jt < 16; ++jt) {
    const int j0 = jt << 8;
    float s[8][8] = {};  // rows 8ty+i; j-cols {tx*4+c, 128+tx*4+c-4}

    // ---- scores: S = (Q/16) @ K^T, D chunked by 32 ----
    for (int dc = 0; dc < 8; ++dc) {
      const int d0 = dc << 5;
      __syncthreads();
#pragma unroll
      for (int l = 0; l < 2; ++l) {
        const int idx = t + (l << 8);
        const int r = idx >> 3, cf = (idx & 7) << 2;
        const float4 qv =
            *(const float4*)(q + base + (size_t)(q0 + r) * D_ + d0 + cf);
        sA[(cf + 0) * 68 + r] = qv.x * 0.0625f;
        sA[(cf + 1) * 68 + r] = qv.y * 0.0625f;
        sA[(cf + 2) * 68 + r] = qv.z * 0.0625f;
        sA[(cf + 3) * 68 + r] = qv.w * 0.0625f;
      }
#pragma unroll
      for (int l = 0; l < 8; ++l) {
        const int idx = t + (l << 8);
        const int j = idx >> 3, cf = (idx & 7) << 2;
        const float4 kv =
            *(const float4*)(k + base + (size_t)(j0 + j) * D_ + d0 + cf);
        sB[(cf + 0) * 260 + j] = kv.x;
        sB[(cf + 1) * 260 + j] = kv.y;
        sB[(cf + 2) * 260 + j] = kv.z;
        sB[(cf + 3) * 260 + j] = kv.w;
      }
      __syncthreads();
#pragma unroll
      for (int dk = 0; dk < 32; ++dk) {
        const float4 a0 = *(const float4*)&sA[dk * 68 + (ty << 3)];
        const float4 a1 = *(const float4*)&sA[dk * 68 + (ty << 3) + 4];
        const float4 b0 = *(const float4*)&sB[dk * 260 + (tx << 2)];
        const float4 b1 = *(const float4*)&sB[dk * 260 + 128 + (tx << 2)];
        const float av[8] = {a0.x, a0.y, a0.z, a0.w, a1.x, a1.y, a1.z, a1.w};
        const float bv[8] = {b0.x, b0.y, b0.z, b0.w, b1.x, b1.y, b1.z, b1.w};
#pragma unroll
        for (int i = 0; i < 8; ++i)
#pragma unroll
          for (int c = 0; c < 8; ++c) s[i][c] += av[i] * bv[c];
      }
    }

    // ---- online softmax, fully in registers (rows live on 32 tx lanes) ----
#pragma unroll
    for (int i = 0; i < 8; ++i) {
      float mx = s[i][0];
#pragma unroll
      for (int c = 1; c < 8; ++c) mx = fmaxf(mx, s[i][c]);
#pragma unroll
      for (int off = 1; off <= 16; off <<= 1)
        mx = fmaxf(mx, __shfl_xor(mx, off, 64));
      const float mnew = fmaxf(m_i[i], mx);
      const float alpha = __expf(m_i[i] - mnew);
      m_i[i] = mnew;
      float sum = 0.f;
#pragma unroll
      for (int c = 0; c < 8; ++c) {
        s[i][c] = __expf(s[i][c] - mnew);
        sum += s[i][c];
      }
#pragma unroll
      for (int off = 1; off <= 16; off <<= 1)
        sum += __shfl_xor(sum, off, 64);
      l_i[i] = l_i[i] * alpha + sum;
#pragma unroll
      for (int c = 0; c < 8; ++c) acc[i][c] *= alpha;
    }

    // ---- PV: ctx += P @ V, j in 2 halves x 4 chunks of 32 ----
#pragma unroll
    for (int half = 0; half < 2; ++half) {      // forced unroll: cb static
      const int cb = half << 2;                 // compile-time after unroll
      for (int sjl = 0; sjl < 4; ++sjl) {       // runtime: LDS addrs only
        __syncthreads();
        // write P^T chunk [jl][qrow]: source j-cols tx*4+cc (half 0) or
        // 128+tx*4+cc (half 1); chunk covers j in [half*128+sjl*32, +32)
        if ((tx >> 3) == sjl) {
#pragma unroll
          for (int cc = 0; cc < 4; ++cc) {
            const int jl = ((tx & 7) << 2) + cc;
            float4 p0, p1;
            p0.x = s[0][cb + cc]; p0.y = s[1][cb + cc];
            p0.z = s[2][cb + cc]; p0.w = s[3][cb + cc];
            p1.x = s[4][cb + cc]; p1.y = s[5][cb + cc];
            p1.z = s[6][cb + cc]; p1.w = s[7][cb + cc];
            *(float4*)&sA[jl * 68 + (ty << 3)]     = p0;
            *(float4*)&sA[jl * 68 + (ty << 3) + 4] = p1;
          }
        }
        // stage V chunk [32 j][256 d], natural layout
#pragma unroll
        for (int l = 0; l < 8; ++l) {
          const int idx = t + (l << 8);
          const int jr = idx >> 6, nc = (idx & 63) << 2;
          *(float4*)&sB[jr * 260 + nc] = *(const float4*)(
              v + base +
              (size_t)(j0 + (half << 7) + (sjl << 5) + jr) * D_ + nc);
        }
        __syncthreads();
#pragma unroll
        for (int jj = 0; jj < 32; ++jj) {
          const float4 p0 = *(const float4*)&sA[jj * 68 + (ty << 3)];
          const float4 p1 = *(const float4*)&sA[jj * 68 + (ty << 3) + 4];
          const float4 v0 = *(const float4*)&sB[jj * 260 + (tx << 2)];
          const float4 v1 = *(const float4*)&sB[jj * 260 + 128 + (tx << 2)];
          const float pv[8] = {p0.x, p0.y, p0.z, p0.w,
                               p1.x, p1.y, p1.z, p1.w};
          const float vv[8] = {v0.x, v0.y, v0.z, v0.w,
                               v1.x, v1.y, v1.z, v1.w};
#pragma unroll
          for (int i = 0; i < 8; ++i)
#pragma unroll
            for (int c = 0; c < 8; ++c) acc[i][c] += pv[i] * vv[c];
        }
      }
    }
  }

  // ---- finalize: divide by l, store ----
#pragma unroll
  for (int i = 0; i < 8; ++i) {
    const float linv = 1.0f / l_i[i];
    float4 o0, o1;
    o0.x = acc[i][0] * linv; o0.y = acc[i][1] * linv;
    o0.z = acc[i][2] * linv; o0.w = acc[i][3] * linv;
    o1.x = acc[i][4] * linv; o1.y = acc[i][5] * linv;
    o1.z = acc[i][6] * linv; o1.w = acc[i][7] * linv;
    float* cp = ctx + base + (size_t)(q0 + (ty << 3) + i) * D_;
    *(float4*)(cp + (tx << 2)) = o0;
    *(float4*)(cp + 128 + (tx << 2)) = o1;
  }
}

// ---------------------------------------------------------------------------
// w[row] = dot(logits[row,:], cv)   — one wave per row, 4 rows per block
// ---------------------------------------------------------------------------
__global__ __launch_bounds__(256) void wdot_kernel(
    const float* __restrict__ logits, const float* __restrict__ cv,
    float* __restrict__ w) {
  const int t    = threadIdx.x;
  const int wave = t >> 6, lane = t & 63;
  const size_t row = (size_t)blockIdx.x * 4 + wave;
  const float4 l4 = *(const float4*)(logits + row * 256 + (lane << 2));
  const float4 c4 = *(const float4*)(cv + (lane << 2));
  float p = l4.x * c4.x + l4.y * c4.y + l4.z * c4.z + l4.w * c4.w;
#pragma unroll
  for (int off = 32; off > 0; off >>= 1) p += __shfl_down(p, off, 64);
  if (lane == 0) w[row] = p;
}

// ---------------------------------------------------------------------------
// softmax over the sequence dim per batch (in place on w) — one block per b
// ---------------------------------------------------------------------------
__global__ __launch_bounds__(256) void seq_softmax_kernel(float* __restrict__ w) {
  __shared__ float red[4];
  const int b = blockIdx.x, t = threadIdx.x;
  const int wave = t >> 6, lane = t & 63;
  float* wb = w + (size_t)b * S_;
  float vals[16];
  float mx = -INFINITY;
#pragma unroll
  for (int i = 0; i < 16; ++i) {
    vals[i] = wb[t + (i << 8)];
    mx = fmaxf(mx, vals[i]);
  }
#pragma unroll
  for (int off = 32; off > 0; off >>= 1) mx = fmaxf(mx, __shfl_xor(mx, off, 64));
  if (lane == 0) red[wave] = mx;
  __syncthreads();
  const float M = fmaxf(fmaxf(red[0], red[1]), fmaxf(red[2], red[3]));
  float sum = 0.f;
#pragma unroll
  for (int i = 0; i < 16; ++i) {
    vals[i] = __expf(vals[i] - M);
    sum += vals[i];
  }
#pragma unroll
  for (int off = 32; off > 0; off >>= 1) sum += __shfl_xor(sum, off, 64);
  __syncthreads();
  if (lane == 0) red[wave] = sum;
  __syncthreads();
  const float inv = 1.0f / (red[0] + red[1] + red[2] + red[3]);
#pragma unroll
  for (int i = 0; i < 16; ++i) wb[t + (i << 8)] = vals[i] * inv;
}

// ---------------------------------------------------------------------------
// out[b,s,:] *= nw[b,s]   (in place on d_out, float4 per thread)
// ---------------------------------------------------------------------------
__global__ __launch_bounds__(256) void scale_kernel(
    float* __restrict__ out, const float* __restrict__ nw) {
  const size_t g = (size_t)blockIdx.x * 256 + threadIdx.x;  // float4 index
  float4* o4 = (float4*)out;
  float4 vv = o4[g];
  const float sc = nw[g >> 6];
  vv.x *= sc; vv.y *= sc; vv.z *= sc; vv.w *= sc;
  o4[g] = vv;
}

// ---------------------------------------------------------------------------
extern "C" void kernel_launch(void* const* d_in, const int* in_sizes, int n_in,
                              void* d_out, int out_size, void* d_ws, size_t ws_size,
                              hipStream_t stream) {
  const float* x  = (const float*)d_in[0];
  const float* Wq = (const float*)d_in[1];
  const float* bq = (const float*)d_in[2];
  const float* Wk = (const float*)d_in[3];
  const float* bk = (const float*)d_in[4];
  const float* Wv = (const float*)d_in[5];
  const float* bv = (const float*)d_in[6];
  const float* Wo = (const float*)d_in[7];
  const float* bo = (const float*)d_in[8];
  const float* cv = (const float*)d_in[9];
  float* out = (float*)d_out;

  const size_t N = (size_t)B_ * S_ * D_;  // 8,388,608
  float* q   = (float*)d_ws;
  float* k   = q + N;
  float* v   = k + N;
  float* ctx = v + N;
  float* w   = ctx + N;  // B*S floats

  gemm_bias_kernel<<<512, 256, 0, stream>>>(x, Wq, bq, q);
  gemm_bias_kernel<<<512, 256, 0, stream>>>(x, Wk, bk, k);
  gemm_bias_kernel<<<512, 256, 0, stream>>>(x, Wv, bv, v);
  flash_attn_kernel<<<dim3(64, 8), 256, 0, stream>>>(q, k, v, ctx);
  gemm_bias_kernel<<<512, 256, 0, stream>>>(ctx, Wo, bo, out);
  wdot_kernel<<<8192, 256, 0, stream>>>(out, cv, w);
  seq_softmax_kernel<<<8, 256, 0, stream>>>(w);
  scale_kernel<<<8192, 256, 0, stream>>>(out, w);
}

// Round 5
// 2639.639 us; speedup vs baseline: 12.0347x; 1.0671x over previous
//
#include <hip/hip_runtime.h>
#include <math.h>
#include <cstddef>
#include <cstdint>

#define B_ 8
#define S_ 4096
#define D_ 256

// ---------------------------------------------------------------------------
// GEMM: C[M,256] = A[M,256] @ W[256,256] + bias   (fp32), natural output.
// Tile 64(M) x 256(N), K chunked by 32. 256 threads = (tx=32) x (ty=8).
// 8x8 micro-tile; thread's 8 N-cols are {tx*4..+3, 128+tx*4..+3}.
// ---------------------------------------------------------------------------
__global__ __launch_bounds__(256, 2) void gemm_bias_kernel(
    const float* __restrict__ A, const float* __restrict__ W,
    const float* __restrict__ bias, float* __restrict__ C) {
  __shared__ __align__(16) float sA[32 * 68];   // A^T chunk [k][m]
  __shared__ __align__(16) float sW[32 * 260];  // W chunk [k][n]
  const int t  = threadIdx.x;
  const int tx = t & 31;
  const int ty = t >> 5;
  const size_t m0 = (size_t)blockIdx.x * 64;

  float acc[8][8] = {};

  for (int kc = 0; kc < 8; ++kc) {
    const int k0 = kc << 5;
    __syncthreads();
#pragma unroll
    for (int l = 0; l < 2; ++l) {
      const int idx = t + (l << 8);
      const int r = idx >> 3, cf = (idx & 7) << 2;
      const float4 a4 = *(const float4*)(A + (m0 + r) * 256 + k0 + cf);
      sA[(cf + 0) * 68 + r] = a4.x;
      sA[(cf + 1) * 68 + r] = a4.y;
      sA[(cf + 2) * 68 + r] = a4.z;
      sA[(cf + 3) * 68 + r] = a4.w;
    }
#pragma unroll
    for (int l = 0; l < 8; ++l) {
      const int idx = t + (l << 8);
      const int kr = idx >> 6, nc = (idx & 63) << 2;
      *(float4*)&sW[kr * 260 + nc] =
          *(const float4*)(W + (size_t)(k0 + kr) * 256 + nc);
    }
    __syncthreads();
#pragma unroll
    for (int kk = 0; kk < 32; ++kk) {
      const float4 a0 = *(const float4*)&sA[kk * 68 + (ty << 3)];
      const float4 a1 = *(const float4*)&sA[kk * 68 + (ty << 3) + 4];
      const float4 b0 = *(const float4*)&sW[kk * 260 + (tx << 2)];
      const float4 b1 = *(const float4*)&sW[kk * 260 + 128 + (tx << 2)];
      const float av[8] = {a0.x, a0.y, a0.z, a0.w, a1.x, a1.y, a1.z, a1.w};
      const float bv[8] = {b0.x, b0.y, b0.z, b0.w, b1.x, b1.y, b1.z, b1.w};
#pragma unroll
      for (int i = 0; i < 8; ++i)
#pragma unroll
        for (int c = 0; c < 8; ++c) acc[i][c] += av[i] * bv[c];
    }
  }

  const float4 bb0 = *(const float4*)(bias + (tx << 2));
  const float4 bb1 = *(const float4*)(bias + 128 + (tx << 2));
#pragma unroll
  for (int i = 0; i < 8; ++i) {
    float4 o0, o1;
    o0.x = acc[i][0] + bb0.x; o0.y = acc[i][1] + bb0.y;
    o0.z = acc[i][2] + bb0.z; o0.w = acc[i][3] + bb0.w;
    o1.x = acc[i][4] + bb1.x; o1.y = acc[i][5] + bb1.y;
    o1.z = acc[i][6] + bb1.z; o1.w = acc[i][7] + bb1.w;
    float* cp = C + (m0 + (ty << 3) + i) * 256;
    *(float4*)(cp + (tx << 2)) = o0;
    *(float4*)(cp + 128 + (tx << 2)) = o1;
  }
}

// ---------------------------------------------------------------------------
// Same GEMM, but writes the output TRANSPOSED per batch: Ct[b][n][s].
// Used for Q and K so the flash kernel can stage Q^T/K^T chunks with pure
// b128 loads/stores (no per-element LDS transpose).
// Thread holds rows m0+8ty..+7 (s-contiguous) per col -> two float4 stores
// along s per col. Scattered 16B stores, but only 8 MB total per GEMM.
// ---------------------------------------------------------------------------
__global__ __launch_bounds__(256, 2) void gemm_bias_t_kernel(
    const float* __restrict__ A, const float* __restrict__ W,
    const float* __restrict__ bias, float* __restrict__ Ct) {
  __shared__ __align__(16) float sA[32 * 68];
  __shared__ __align__(16) float sW[32 * 260];
  const int t  = threadIdx.x;
  const int tx = t & 31;
  const int ty = t >> 5;
  const size_t m0 = (size_t)blockIdx.x * 64;

  float acc[8][8] = {};

  for (int kc = 0; kc < 8; ++kc) {
    const int k0 = kc << 5;
    __syncthreads();
#pragma unroll
    for (int l = 0; l < 2; ++l) {
      const int idx = t + (l << 8);
      const int r = idx >> 3, cf = (idx & 7) << 2;
      const float4 a4 = *(const float4*)(A + (m0 + r) * 256 + k0 + cf);
      sA[(cf + 0) * 68 + r] = a4.x;
      sA[(cf + 1) * 68 + r] = a4.y;
      sA[(cf + 2) * 68 + r] = a4.z;
      sA[(cf + 3) * 68 + r] = a4.w;
    }
#pragma unroll
    for (int l = 0; l < 8; ++l) {
      const int idx = t + (l << 8);
      const int kr = idx >> 6, nc = (idx & 63) << 2;
      *(float4*)&sW[kr * 260 + nc] =
          *(const float4*)(W + (size_t)(k0 + kr) * 256 + nc);
    }
    __syncthreads();
#pragma unroll
    for (int kk = 0; kk < 32; ++kk) {
      const float4 a0 = *(const float4*)&sA[kk * 68 + (ty << 3)];
      const float4 a1 = *(const float4*)&sA[kk * 68 + (ty << 3) + 4];
      const float4 b0 = *(const float4*)&sW[kk * 260 + (tx << 2)];
      const float4 b1 = *(const float4*)&sW[kk * 260 + 128 + (tx << 2)];
      const float av[8] = {a0.x, a0.y, a0.z, a0.w, a1.x, a1.y, a1.z, a1.w};
      const float bv[8] = {b0.x, b0.y, b0.z, b0.w, b1.x, b1.y, b1.z, b1.w};
#pragma unroll
      for (int i = 0; i < 8; ++i)
#pragma unroll
        for (int c = 0; c < 8; ++c) acc[i][c] += av[i] * bv[c];
    }
  }

  // transposed epilogue: Ct[b][n][s], block rows all in batch b = m0>>12
  const size_t cb =
      (size_t)(m0 >> 12) * (D_ * (size_t)S_) + (m0 & 4095) + (ty << 3);
#pragma unroll
  for (int c = 0; c < 8; ++c) {
    const int n = (c < 4) ? ((tx << 2) + c) : (128 + (tx << 2) + (c - 4));
    const float bn = bias[n];
    float4 o0, o1;
    o0.x = acc[0][c] + bn; o0.y = acc[1][c] + bn;
    o0.z = acc[2][c] + bn; o0.w = acc[3][c] + bn;
    o1.x = acc[4][c] + bn; o1.y = acc[5][c] + bn;
    o1.z = acc[6][c] + bn; o1.w = acc[7][c] + bn;
    *(float4*)(Ct + cb + (size_t)n * S_)     = o0;
    *(float4*)(Ct + cb + (size_t)n * S_ + 4) = o1;
  }
}

// ---------------------------------------------------------------------------
// Flash attention, fp32.  Grid (S/64, B), 256 threads = (tx=32) x (ty=8).
// Inputs qt/kt are TRANSPOSED [b][d][s]; v natural [b][s][d].
// Staging is pure float4 load -> b128 LDS store (no element transposes).
// waves_per_eu(2,2): grid caps us at 2 blocks/CU anyway; freeing the VGPR
// budget to ~256 eliminates the scratch spill that round 4's counters showed
// (flash WRITE_SIZE 1.9 GB vs 32 MB ideal at forced VGPR=128).
// ---------------------------------------------------------------------------
__global__ __launch_bounds__(256)
__attribute__((amdgpu_waves_per_eu(2, 2)))
void flash_attn_kernel(
    const float* __restrict__ qt, const float* __restrict__ kt,
    const float* __restrict__ v, float* __restrict__ ctx) {
  __shared__ __align__(16) float sA[32 * 68];   // Q^T chunk | pT chunk
  __shared__ __align__(16) float sB[32 * 260];  // K^T chunk | V chunk
  const int t  = threadIdx.x;
  const int tx = t & 31;
  const int ty = t >> 5;
  const int q0 = blockIdx.x * 64;
  const size_t base = (size_t)blockIdx.y * (S_ * (size_t)D_);  // also qt/kt base

  float acc[8][8] = {};   // rows 8ty+i; d-cols {tx*4+c, 128+tx*4+c-4}
  float m_i[8], l_i[8];
#pragma unroll
  for (int i = 0; i < 8; ++i) { m_i[i] = -INFINITY; l_i[i] = 0.f; }

  for (int jt = 0; jt < 16; ++jt) {
    const int j0 = jt << 8;
    float s[8][8] = {};  // rows 8ty+i; j-cols {tx*4+c, 128+tx*4+c-4}

    // ---- scores: S = (Q/16) @ K^T, D chunked by 32 ----
    for (int dc = 0; dc < 8; ++dc) {
      const int d0 = dc << 5;
      __syncthreads();
      // stage Q^T chunk [32 dk][64 r] from qt[b][d][s]: 2 f4/thread
#pragma unroll
      for (int l = 0; l < 2; ++l) {
        const int idx = t + (l << 8);
        const int dk = idx >> 4, rf = (idx & 15) << 2;
        float4 qv =
            *(const float4*)(qt + base + (size_t)(d0 + dk) * S_ + q0 + rf);
        qv.x *= 0.0625f; qv.y *= 0.0625f; qv.z *= 0.0625f; qv.w *= 0.0625f;
        *(float4*)&sA[dk * 68 + rf] = qv;
      }
      // stage K^T chunk [32 dk][256 j] from kt[b][d][s]: 8 f4/thread
#pragma unroll
      for (int l = 0; l < 8; ++l) {
        const int idx = t + (l << 8);
        const int dk = idx >> 6, jf = (idx & 63) << 2;
        *(float4*)&sB[dk * 260 + jf] =
            *(const float4*)(kt + base + (size_t)(d0 + dk) * S_ + j0 + jf);
      }
      __syncthreads();
#pragma unroll
      for (int dk = 0; dk < 32; ++dk) {
        const float4 a0 = *(const float4*)&sA[dk * 68 + (ty << 3)];
        const float4 a1 = *(const float4*)&sA[dk * 68 + (ty << 3) + 4];
        const float4 b0 = *(const float4*)&sB[dk * 260 + (tx << 2)];
        const float4 b1 = *(const float4*)&sB[dk * 260 + 128 + (tx << 2)];
        const float av[8] = {a0.x, a0.y, a0.z, a0.w, a1.x, a1.y, a1.z, a1.w};
        const float bv[8] = {b0.x, b0.y, b0.z, b0.w, b1.x, b1.y, b1.z, b1.w};
#pragma unroll
        for (int i = 0; i < 8; ++i)
#pragma unroll
          for (int c = 0; c < 8; ++c) s[i][c] += av[i] * bv[c];
      }
    }

    // ---- online softmax, fully in registers (rows live on 32 tx lanes) ----
#pragma unroll
    for (int i = 0; i < 8; ++i) {
      float mx = s[i][0];
#pragma unroll
      for (int c = 1; c < 8; ++c) mx = fmaxf(mx, s[i][c]);
#pragma unroll
      for (int off = 1; off <= 16; off <<= 1)
        mx = fmaxf(mx, __shfl_xor(mx, off, 64));
      const float mnew = fmaxf(m_i[i], mx);
      const float alpha = __expf(m_i[i] - mnew);
      m_i[i] = mnew;
      float sum = 0.f;
#pragma unroll
      for (int c = 0; c < 8; ++c) {
        s[i][c] = __expf(s[i][c] - mnew);
        sum += s[i][c];
      }
#pragma unroll
      for (int off = 1; off <= 16; off <<= 1)
        sum += __shfl_xor(sum, off, 64);
      l_i[i] = l_i[i] * alpha + sum;
#pragma unroll
      for (int c = 0; c < 8; ++c) acc[i][c] *= alpha;
    }

    // ---- PV: ctx += P @ V, j in 2 halves x 4 chunks of 32 ----
#pragma unroll
    for (int half = 0; half < 2; ++half) {      // forced unroll: cb static
      const int cb = half << 2;                 // compile-time after unroll
      for (int sjl = 0; sjl < 4; ++sjl) {       // runtime: LDS addrs only
        __syncthreads();
        // write P^T chunk [jl][qrow]
        if ((tx >> 3) == sjl) {
#pragma unroll
          for (int cc = 0; cc < 4; ++cc) {
            const int jl = ((tx & 7) << 2) + cc;
            float4 p0, p1;
            p0.x = s[0][cb + cc]; p0.y = s[1][cb + cc];
            p0.z = s[2][cb + cc]; p0.w = s[3][cb + cc];
            p1.x = s[4][cb + cc]; p1.y = s[5][cb + cc];
            p1.z = s[6][cb + cc]; p1.w = s[7][cb + cc];
            *(float4*)&sA[jl * 68 + (ty << 3)]     = p0;
            *(float4*)&sA[jl * 68 + (ty << 3) + 4] = p1;
          }
        }
        // stage V chunk [32 j][256 d], natural layout
#pragma unroll
        for (int l = 0; l < 8; ++l) {
          const int idx = t + (l << 8);
          const int jr = idx >> 6, nc = (idx & 63) << 2;
          *(float4*)&sB[jr * 260 + nc] = *(const float4*)(
              v + base +
              (size_t)(j0 + (half << 7) + (sjl << 5) + jr) * D_ + nc);
        }
        __syncthreads();
#pragma unroll
        for (int jj = 0; jj < 32; ++jj) {
          const float4 p0 = *(const float4*)&sA[jj * 68 + (ty << 3)];
          const float4 p1 = *(const float4*)&sA[jj * 68 + (ty << 3) + 4];
          const float4 v0 = *(const float4*)&sB[jj * 260 + (tx << 2)];
          const float4 v1 = *(const float4*)&sB[jj * 260 + 128 + (tx << 2)];
          const float pv[8] = {p0.x, p0.y, p0.z, p0.w,
                               p1.x, p1.y, p1.z, p1.w};
          const float vv[8] = {v0.x, v0.y, v0.z, v0.w,
                               v1.x, v1.y, v1.z, v1.w};
#pragma unroll
          for (int i = 0; i < 8; ++i)
#pragma unroll
            for (int c = 0; c < 8; ++c) acc[i][c] += pv[i] * vv[c];
        }
      }
    }
  }

  // ---- finalize: divide by l, store ----
#pragma unroll
  for (int i = 0; i < 8; ++i) {
    const float linv = 1.0f / l_i[i];
    float4 o0, o1;
    o0.x = acc[i][0] * linv; o0.y = acc[i][1] * linv;
    o0.z = acc[i][2] * linv; o0.w = acc[i][3] * linv;
    o1.x = acc[i][4] * linv; o1.y = acc[i][5] * linv;
    o1.z = acc[i][6] * linv; o1.w = acc[i][7] * linv;
    float* cp = ctx + base + (size_t)(q0 + (ty << 3) + i) * D_;
    *(float4*)(cp + (tx << 2)) = o0;
    *(float4*)(cp + 128 + (tx << 2)) = o1;
  }
}

// ---------------------------------------------------------------------------
// w[row] = dot(logits[row,:], cv)   — one wave per row, 4 rows per block
// ---------------------------------------------------------------------------
__global__ __launch_bounds__(256) void wdot_kernel(
    const float* __restrict__ logits, const float* __restrict__ cv,
    float* __restrict__ w) {
  const int t    = threadIdx.x;
  const int wave = t >> 6, lane = t & 63;
  const size_t row = (size_t)blockIdx.x * 4 + wave;
  const float4 l4 = *(const float4*)(logits + row * 256 + (lane << 2));
  const float4 c4 = *(const float4*)(cv + (lane << 2));
  float p = l4.x * c4.x + l4.y * c4.y + l4.z * c4.z + l4.w * c4.w;
#pragma unroll
  for (int off = 32; off > 0; off >>= 1) p += __shfl_down(p, off, 64);
  if (lane == 0) w[row] = p;
}

// ---------------------------------------------------------------------------
// softmax over the sequence dim per batch (in place on w) — one block per b
// ---------------------------------------------------------------------------
__global__ __launch_bounds__(256) void seq_softmax_kernel(float* __restrict__ w) {
  __shared__ float red[4];
  const int b = blockIdx.x, t = threadIdx.x;
  const int wave = t >> 6, lane = t & 63;
  float* wb = w + (size_t)b * S_;
  float vals[16];
  float mx = -INFINITY;
#pragma unroll
  for (int i = 0; i < 16; ++i) {
    vals[i] = wb[t + (i << 8)];
    mx = fmaxf(mx, vals[i]);
  }
#pragma unroll
  for (int off = 32; off > 0; off >>= 1) mx = fmaxf(mx, __shfl_xor(mx, off, 64));
  if (lane == 0) red[wave] = mx;
  __syncthreads();
  const float M = fmaxf(fmaxf(red[0], red[1]), fmaxf(red[2], red[3]));
  float sum = 0.f;
#pragma unroll
  for (int i = 0; i < 16; ++i) {
    vals[i] = __expf(vals[i] - M);
    sum += vals[i];
  }
#pragma unroll
  for (int off = 32; off > 0; off >>= 1) sum += __shfl_xor(sum, off, 64);
  __syncthreads();
  if (lane == 0) red[wave] = sum;
  __syncthreads();
  const float inv = 1.0f / (red[0] + red[1] + red[2] + red[3]);
#pragma unroll
  for (int i = 0; i < 16; ++i) wb[t + (i << 8)] = vals[i] * inv;
}

// ---------------------------------------------------------------------------
// out[b,s,:] *= nw[b,s]   (in place on d_out, float4 per thread)
// ---------------------------------------------------------------------------
__global__ __launch_bounds__(256) void scale_kernel(
    float* __restrict__ out, const float* __restrict__ nw) {
  const size_t g = (size_t)blockIdx.x * 256 + threadIdx.x;  // float4 index
  float4* o4 = (float4*)out;
  float4 vv = o4[g];
  const float sc = nw[g >> 6];
  vv.x *= sc; vv.y *= sc; vv.z *= sc; vv.w *= sc;
  o4[g] = vv;
}

// ---------------------------------------------------------------------------
extern "C" void kernel_launch(void* const* d_in, const int* in_sizes, int n_in,
                              void* d_out, int out_size, void* d_ws, size_t ws_size,
                              hipStream_t stream) {
  const float* x  = (const float*)d_in[0];
  const float* Wq = (const float*)d_in[1];
  const float* bq = (const float*)d_in[2];
  const float* Wk = (const float*)d_in[3];
  const float* bk = (const float*)d_in[4];
  const float* Wv = (const float*)d_in[5];
  const float* bv = (const float*)d_in[6];
  const float* Wo = (const float*)d_in[7];
  const float* bo = (const float*)d_in[8];
  const float* cv = (const float*)d_in[9];
  float* out = (float*)d_out;

  const size_t N = (size_t)B_ * S_ * D_;  // 8,388,608
  float* qt  = (float*)d_ws;   // [B][D][S] transposed
  float* kt  = qt + N;         // [B][D][S] transposed
  float* v   = kt + N;         // [B][S][D] natural
  float* ctx = v + N;          // [B][S][D]
  float* w   = ctx + N;        // B*S floats

  gemm_bias_t_kernel<<<512, 256, 0, stream>>>(x, Wq, bq, qt);
  gemm_bias_t_kernel<<<512, 256, 0, stream>>>(x, Wk, bk, kt);
  gemm_bias_kernel<<<512, 256, 0, stream>>>(x, Wv, bv, v);
  flash_attn_kernel<<<dim3(64, 8), 256, 0, stream>>>(qt, kt, v, ctx);
  gemm_bias_kernel<<<512, 256, 0, stream>>>(ctx, Wo, bo, out);
  wdot_kernel<<<8192, 256, 0, stream>>>(out, cv, w);
  seq_softmax_kernel<<<8, 256, 0, stream>>>(w);
  scale_kernel<<<8192, 256, 0, stream>>>(out, w);
}

// Round 6
// 2250.304 us; speedup vs baseline: 14.1168x; 1.1730x over previous
//
#include <hip/hip_runtime.h>
#include <math.h>
#include <cstddef>
#include <cstdint>

#define B_ 8
#define S_ 4096
#define D_ 256

// ---------------------------------------------------------------------------
// GEMM: C[M,256] = A[M,256] @ W[256,256] + bias   (fp32), natural output.
// Tile 64(M) x 256(N), K chunked by 32. 256 threads = (tx=32) x (ty=8).
// 8x8 micro-tile; thread's 8 N-cols are {tx*4..+3, 128+tx*4..+3}.
// ---------------------------------------------------------------------------
__global__ __launch_bounds__(256, 2) void gemm_bias_kernel(
    const float* __restrict__ A, const float* __restrict__ W,
    const float* __restrict__ bias, float* __restrict__ C) {
  __shared__ __align__(16) float sA[32 * 68];   // A^T chunk [k][m]
  __shared__ __align__(16) float sW[32 * 260];  // W chunk [k][n]
  const int t  = threadIdx.x;
  const int tx = t & 31;
  const int ty = t >> 5;
  const size_t m0 = (size_t)blockIdx.x * 64;

  float acc[8][8] = {};

  for (int kc = 0; kc < 8; ++kc) {
    const int k0 = kc << 5;
    __syncthreads();
#pragma unroll
    for (int l = 0; l < 2; ++l) {
      const int idx = t + (l << 8);
      const int r = idx >> 3, cf = (idx & 7) << 2;
      const float4 a4 = *(const float4*)(A + (m0 + r) * 256 + k0 + cf);
      sA[(cf + 0) * 68 + r] = a4.x;
      sA[(cf + 1) * 68 + r] = a4.y;
      sA[(cf + 2) * 68 + r] = a4.z;
      sA[(cf + 3) * 68 + r] = a4.w;
    }
#pragma unroll
    for (int l = 0; l < 8; ++l) {
      const int idx = t + (l << 8);
      const int kr = idx >> 6, nc = (idx & 63) << 2;
      *(float4*)&sW[kr * 260 + nc] =
          *(const float4*)(W + (size_t)(k0 + kr) * 256 + nc);
    }
    __syncthreads();
#pragma unroll
    for (int kk = 0; kk < 32; ++kk) {
      const float4 a0 = *(const float4*)&sA[kk * 68 + (ty << 3)];
      const float4 a1 = *(const float4*)&sA[kk * 68 + (ty << 3) + 4];
      const float4 b0 = *(const float4*)&sW[kk * 260 + (tx << 2)];
      const float4 b1 = *(const float4*)&sW[kk * 260 + 128 + (tx << 2)];
      const float av[8] = {a0.x, a0.y, a0.z, a0.w, a1.x, a1.y, a1.z, a1.w};
      const float bv[8] = {b0.x, b0.y, b0.z, b0.w, b1.x, b1.y, b1.z, b1.w};
#pragma unroll
      for (int i = 0; i < 8; ++i)
#pragma unroll
        for (int c = 0; c < 8; ++c) acc[i][c] += av[i] * bv[c];
    }
  }

  const float4 bb0 = *(const float4*)(bias + (tx << 2));
  const float4 bb1 = *(const float4*)(bias + 128 + (tx << 2));
#pragma unroll
  for (int i = 0; i < 8; ++i) {
    float4 o0, o1;
    o0.x = acc[i][0] + bb0.x; o0.y = acc[i][1] + bb0.y;
    o0.z = acc[i][2] + bb0.z; o0.w = acc[i][3] + bb0.w;
    o1.x = acc[i][4] + bb1.x; o1.y = acc[i][5] + bb1.y;
    o1.z = acc[i][6] + bb1.z; o1.w = acc[i][7] + bb1.w;
    float* cp = C + (m0 + (ty << 3) + i) * 256;
    *(float4*)(cp + (tx << 2)) = o0;
    *(float4*)(cp + 128 + (tx << 2)) = o1;
  }
}

// ---------------------------------------------------------------------------
// Same GEMM, but writes the output TRANSPOSED per batch: Ct[b][n][s].
// Used for Q and K so the flash kernel can stage Q^T/K^T chunks with pure
// b128 loads/stores (no per-element LDS transpose).
// ---------------------------------------------------------------------------
__global__ __launch_bounds__(256, 2) void gemm_bias_t_kernel(
    const float* __restrict__ A, const float* __restrict__ W,
    const float* __restrict__ bias, float* __restrict__ Ct) {
  __shared__ __align__(16) float sA[32 * 68];
  __shared__ __align__(16) float sW[32 * 260];
  const int t  = threadIdx.x;
  const int tx = t & 31;
  const int ty = t >> 5;
  const size_t m0 = (size_t)blockIdx.x * 64;

  float acc[8][8] = {};

  for (int kc = 0; kc < 8; ++kc) {
    const int k0 = kc << 5;
    __syncthreads();
#pragma unroll
    for (int l = 0; l < 2; ++l) {
      const int idx = t + (l << 8);
      const int r = idx >> 3, cf = (idx & 7) << 2;
      const float4 a4 = *(const float4*)(A + (m0 + r) * 256 + k0 + cf);
      sA[(cf + 0) * 68 + r] = a4.x;
      sA[(cf + 1) * 68 + r] = a4.y;
      sA[(cf + 2) * 68 + r] = a4.z;
      sA[(cf + 3) * 68 + r] = a4.w;
    }
#pragma unroll
    for (int l = 0; l < 8; ++l) {
      const int idx = t + (l << 8);
      const int kr = idx >> 6, nc = (idx & 63) << 2;
      *(float4*)&sW[kr * 260 + nc] =
          *(const float4*)(W + (size_t)(k0 + kr) * 256 + nc);
    }
    __syncthreads();
#pragma unroll
    for (int kk = 0; kk < 32; ++kk) {
      const float4 a0 = *(const float4*)&sA[kk * 68 + (ty << 3)];
      const float4 a1 = *(const float4*)&sA[kk * 68 + (ty << 3) + 4];
      const float4 b0 = *(const float4*)&sW[kk * 260 + (tx << 2)];
      const float4 b1 = *(const float4*)&sW[kk * 260 + 128 + (tx << 2)];
      const float av[8] = {a0.x, a0.y, a0.z, a0.w, a1.x, a1.y, a1.z, a1.w};
      const float bv[8] = {b0.x, b0.y, b0.z, b0.w, b1.x, b1.y, b1.z, b1.w};
#pragma unroll
      for (int i = 0; i < 8; ++i)
#pragma unroll
        for (int c = 0; c < 8; ++c) acc[i][c] += av[i] * bv[c];
    }
  }

  // transposed epilogue: Ct[b][n][s], block rows all in batch b = m0>>12
  const size_t cb =
      (size_t)(m0 >> 12) * (D_ * (size_t)S_) + (m0 & 4095) + (ty << 3);
#pragma unroll
  for (int c = 0; c < 8; ++c) {
    const int n = (c < 4) ? ((tx << 2) + c) : (128 + (tx << 2) + (c - 4));
    const float bn = bias[n];
    float4 o0, o1;
    o0.x = acc[0][c] + bn; o0.y = acc[1][c] + bn;
    o0.z = acc[2][c] + bn; o0.w = acc[3][c] + bn;
    o1.x = acc[4][c] + bn; o1.y = acc[5][c] + bn;
    o1.z = acc[6][c] + bn; o1.w = acc[7][c] + bn;
    *(float4*)(Ct + cb + (size_t)n * S_)     = o0;
    *(float4*)(Ct + cb + (size_t)n * S_ + 4) = o1;
  }
}

// ---------------------------------------------------------------------------
// Flash attention, fp32.  Grid (S/64, B), 256 threads = (tx=32) x (ty=8).
// Inputs qt/kt TRANSPOSED [b][d][s]; v natural [b][s][d].
// __launch_bounds__(256, 1): min 1 wave/EU -> VGPR budget 512. The kernel
// needs ~170 live regs (acc 64 + s 64 + m/l 16 + temps); every prior config
// ((256,2), waves_per_eu(2,2)) pinned the allocator at 128 and spilled
// ~1.9 GB/dispatch each way to scratch (rocprof WRITE_SIZE). At ~200 regs
// the HW still runs 2 waves/EU, so occupancy is unchanged.
// ---------------------------------------------------------------------------
__global__ __launch_bounds__(256, 1)
void flash_attn_kernel(
    const float* __restrict__ qt, const float* __restrict__ kt,
    const float* __restrict__ v, float* __restrict__ ctx) {
  __shared__ __align__(16) float sA[32 * 68];   // Q^T chunk | pT chunk
  __shared__ __align__(16) float sB[32 * 260];  // K^T chunk | V chunk
  const int t  = threadIdx.x;
  const int tx = t & 31;
  const int ty = t >> 5;
  const int q0 = blockIdx.x * 64;
  const size_t base = (size_t)blockIdx.y * (S_ * (size_t)D_);

  float acc[8][8] = {};   // rows 8ty+i; d-cols {tx*4+c, 128+tx*4+c-4}
  float m_i[8], l_i[8];
#pragma unroll
  for (int i = 0; i < 8; ++i) { m_i[i] = -INFINITY; l_i[i] = 0.f; }

  for (int jt = 0; jt < 16; ++jt) {
    const int j0 = jt << 8;
    float s[8][8] = {};  // rows 8ty+i; j-cols {tx*4+c, 128+tx*4+c-4}

    // ---- scores: S = (Q/16) @ K^T, D chunked by 32 ----
    for (int dc = 0; dc < 8; ++dc) {
      const int d0 = dc << 5;
      __syncthreads();
      // stage Q^T chunk [32 dk][64 r] from qt[b][d][s]: 2 f4/thread
#pragma unroll
      for (int l = 0; l < 2; ++l) {
        const int idx = t + (l << 8);
        const int dk = idx >> 4, rf = (idx & 15) << 2;
        float4 qv =
            *(const float4*)(qt + base + (size_t)(d0 + dk) * S_ + q0 + rf);
        qv.x *= 0.0625f; qv.y *= 0.0625f; qv.z *= 0.0625f; qv.w *= 0.0625f;
        *(float4*)&sA[dk * 68 + rf] = qv;
      }
      // stage K^T chunk [32 dk][256 j] from kt[b][d][s]: 8 f4/thread
#pragma unroll
      for (int l = 0; l < 8; ++l) {
        const int idx = t + (l << 8);
        const int dk = idx >> 6, jf = (idx & 63) << 2;
        *(float4*)&sB[dk * 260 + jf] =
            *(const float4*)(kt + base + (size_t)(d0 + dk) * S_ + j0 + jf);
      }
      __syncthreads();
#pragma unroll
      for (int dk = 0; dk < 32; ++dk) {
        const float4 a0 = *(const float4*)&sA[dk * 68 + (ty << 3)];
        const float4 a1 = *(const float4*)&sA[dk * 68 + (ty << 3) + 4];
        const float4 b0 = *(const float4*)&sB[dk * 260 + (tx << 2)];
        const float4 b1 = *(const float4*)&sB[dk * 260 + 128 + (tx << 2)];
        const float av[8] = {a0.x, a0.y, a0.z, a0.w, a1.x, a1.y, a1.z, a1.w};
        const float bv[8] = {b0.x, b0.y, b0.z, b0.w, b1.x, b1.y, b1.z, b1.w};
#pragma unroll
        for (int i = 0; i < 8; ++i)
#pragma unroll
          for (int c = 0; c < 8; ++c) s[i][c] += av[i] * bv[c];
      }
    }

    // ---- online softmax, fully in registers (rows live on 32 tx lanes) ----
#pragma unroll
    for (int i = 0; i < 8; ++i) {
      float mx = s[i][0];
#pragma unroll
      for (int c = 1; c < 8; ++c) mx = fmaxf(mx, s[i][c]);
#pragma unroll
      for (int off = 1; off <= 16; off <<= 1)
        mx = fmaxf(mx, __shfl_xor(mx, off, 64));
      const float mnew = fmaxf(m_i[i], mx);
      const float alpha = __expf(m_i[i] - mnew);
      m_i[i] = mnew;
      float sum = 0.f;
#pragma unroll
      for (int c = 0; c < 8; ++c) {
        s[i][c] = __expf(s[i][c] - mnew);
        sum += s[i][c];
      }
#pragma unroll
      for (int off = 1; off <= 16; off <<= 1)
        sum += __shfl_xor(sum, off, 64);
      l_i[i] = l_i[i] * alpha + sum;
#pragma unroll
      for (int c = 0; c < 8; ++c) acc[i][c] *= alpha;
    }

    // ---- PV: ctx += P @ V, j in 2 halves x 4 chunks of 32 ----
#pragma unroll
    for (int half = 0; half < 2; ++half) {      // forced unroll: cb static
      const int cb = half << 2;                 // compile-time after unroll
      for (int sjl = 0; sjl < 4; ++sjl) {       // runtime: LDS addrs only
        __syncthreads();
        // write P^T chunk [jl][qrow]
        if ((tx >> 3) == sjl) {
#pragma unroll
          for (int cc = 0; cc < 4; ++cc) {
            const int jl = ((tx & 7) << 2) + cc;
            float4 p0, p1;
            p0.x = s[0][cb + cc]; p0.y = s[1][cb + cc];
            p0.z = s[2][cb + cc]; p0.w = s[3][cb + cc];
            p1.x = s[4][cb + cc]; p1.y = s[5][cb + cc];
            p1.z = s[6][cb + cc]; p1.w = s[7][cb + cc];
            *(float4*)&sA[jl * 68 + (ty << 3)]     = p0;
            *(float4*)&sA[jl * 68 + (ty << 3) + 4] = p1;
          }
        }
        // stage V chunk [32 j][256 d], natural layout
#pragma unroll
        for (int l = 0; l < 8; ++l) {
          const int idx = t + (l << 8);
          const int jr = idx >> 6, nc = (idx & 63) << 2;
          *(float4*)&sB[jr * 260 + nc] = *(const float4*)(
              v + base +
              (size_t)(j0 + (half << 7) + (sjl << 5) + jr) * D_ + nc);
        }
        __syncthreads();
#pragma unroll
        for (int jj = 0; jj < 32; ++jj) {
          const float4 p0 = *(const float4*)&sA[jj * 68 + (ty << 3)];
          const float4 p1 = *(const float4*)&sA[jj * 68 + (ty << 3) + 4];
          const float4 v0 = *(const float4*)&sB[jj * 260 + (tx << 2)];
          const float4 v1 = *(const float4*)&sB[jj * 260 + 128 + (tx << 2)];
          const float pv[8] = {p0.x, p0.y, p0.z, p0.w,
                               p1.x, p1.y, p1.z, p1.w};
          const float vv[8] = {v0.x, v0.y, v0.z, v0.w,
                               v1.x, v1.y, v1.z, v1.w};
#pragma unroll
          for (int i = 0; i < 8; ++i)
#pragma unroll
            for (int c = 0; c < 8; ++c) acc[i][c] += pv[i] * vv[c];
        }
      }
    }
  }

  // ---- finalize: divide by l, store ----
#pragma unroll
  for (int i = 0; i < 8; ++i) {
    const float linv = 1.0f / l_i[i];
    float4 o0, o1;
    o0.x = acc[i][0] * linv; o0.y = acc[i][1] * linv;
    o0.z = acc[i][2] * linv; o0.w = acc[i][3] * linv;
    o1.x = acc[i][4] * linv; o1.y = acc[i][5] * linv;
    o1.z = acc[i][6] * linv; o1.w = acc[i][7] * linv;
    float* cp = ctx + base + (size_t)(q0 + (ty << 3) + i) * D_;
    *(float4*)(cp + (tx << 2)) = o0;
    *(float4*)(cp + 128 + (tx << 2)) = o1;
  }
}

// ---------------------------------------------------------------------------
// w[row] = dot(logits[row,:], cv)   — one wave per row, 4 rows per block
// ---------------------------------------------------------------------------
__global__ __launch_bounds__(256) void wdot_kernel(
    const float* __restrict__ logits, const float* __restrict__ cv,
    float* __restrict__ w) {
  const int t    = threadIdx.x;
  const int wave = t >> 6, lane = t & 63;
  const size_t row = (size_t)blockIdx.x * 4 + wave;
  const float4 l4 = *(const float4*)(logits + row * 256 + (lane << 2));
  const float4 c4 = *(const float4*)(cv + (lane << 2));
  float p = l4.x * c4.x + l4.y * c4.y + l4.z * c4.z + l4.w * c4.w;
#pragma unroll
  for (int off = 32; off > 0; off >>= 1) p += __shfl_down(p, off, 64);
  if (lane == 0) w[row] = p;
}

// ---------------------------------------------------------------------------
// softmax over the sequence dim per batch (in place on w) — one block per b
// ---------------------------------------------------------------------------
__global__ __launch_bounds__(256) void seq_softmax_kernel(float* __restrict__ w) {
  __shared__ float red[4];
  const int b = blockIdx.x, t = threadIdx.x;
  const int wave = t >> 6, lane = t & 63;
  float* wb = w + (size_t)b * S_;
  float vals[16];
  float mx = -INFINITY;
#pragma unroll
  for (int i = 0; i < 16; ++i) {
    vals[i] = wb[t + (i << 8)];
    mx = fmaxf(mx, vals[i]);
  }
#pragma unroll
  for (int off = 32; off > 0; off >>= 1) mx = fmaxf(mx, __shfl_xor(mx, off, 64));
  if (lane == 0) red[wave] = mx;
  __syncthreads();
  const float M = fmaxf(fmaxf(red[0], red[1]), fmaxf(red[2], red[3]));
  float sum = 0.f;
#pragma unroll
  for (int i = 0; i < 16; ++i) {
    vals[i] = __expf(vals[i] - M);
    sum += vals[i];
  }
#pragma unroll
  for (int off = 32; off > 0; off >>= 1) sum += __shfl_xor(sum, off, 64);
  __syncthreads();
  if (lane == 0) red[wave] = sum;
  __syncthreads();
  const float inv = 1.0f / (red[0] + red[1] + red[2] + red[3]);
#pragma unroll
  for (int i = 0; i < 16; ++i) wb[t + (i << 8)] = vals[i] * inv;
}

// ---------------------------------------------------------------------------
// out[b,s,:] *= nw[b,s]   (in place on d_out, float4 per thread)
// ---------------------------------------------------------------------------
__global__ __launch_bounds__(256) void scale_kernel(
    float* __restrict__ out, const float* __restrict__ nw) {
  const size_t g = (size_t)blockIdx.x * 256 + threadIdx.x;  // float4 index
  float4* o4 = (float4*)out;
  float4 vv = o4[g];
  const float sc = nw[g >> 6];
  vv.x *= sc; vv.y *= sc; vv.z *= sc; vv.w *= sc;
  o4[g] = vv;
}

// ---------------------------------------------------------------------------
extern "C" void kernel_launch(void* const* d_in, const int* in_sizes, int n_in,
                              void* d_out, int out_size, void* d_ws, size_t ws_size,
                              hipStream_t stream) {
  const float* x  = (const float*)d_in[0];
  const float* Wq = (const float*)d_in[1];
  const float* bq = (const float*)d_in[2];
  const float* Wk = (const float*)d_in[3];
  const float* bk = (const float*)d_in[4];
  const float* Wv = (const float*)d_in[5];
  const float* bv = (const float*)d_in[6];
  const float* Wo = (const float*)d_in[7];
  const float* bo = (const float*)d_in[8];
  const float* cv = (const float*)d_in[9];
  float* out = (float*)d_out;

  const size_t N = (size_t)B_ * S_ * D_;  // 8,388,608
  float* qt  = (float*)d_ws;   // [B][D][S] transposed
  float* kt  = qt + N;         // [B][D][S] transposed
  float* v   = kt + N;         // [B][S][D] natural
  float* ctx = v + N;          // [B][S][D]
  float* w   = ctx + N;        // B*S floats

  gemm_bias_t_kernel<<<512, 256, 0, stream>>>(x, Wq, bq, qt);
  gemm_bias_t_kernel<<<512, 256, 0, stream>>>(x, Wk, bk, kt);
  gemm_bias_kernel<<<512, 256, 0, stream>>>(x, Wv, bv, v);
  flash_attn_kernel<<<dim3(64, 8), 256, 0, stream>>>(qt, kt, v, ctx);
  gemm_bias_kernel<<<512, 256, 0, stream>>>(ctx, Wo, bo, out);
  wdot_kernel<<<8192, 256, 0, stream>>>(out, cv, w);
  seq_softmax_kernel<<<8, 256, 0, stream>>>(w);
  scale_kernel<<<8192, 256, 0, stream>>>(out, w);
}

// Round 7
// 1258.789 us; speedup vs baseline: 25.2363x; 1.7877x over previous
//
#include <hip/hip_runtime.h>
#include <math.h>
#include <cstddef>
#include <cstdint>

#define B_ 8
#define S_ 4096
#define D_ 256

typedef __attribute__((ext_vector_type(8))) short short8v;   // 8 bf16 (4 VGPR)
typedef __attribute__((ext_vector_type(4))) short short4v;   // 4 bf16 (8 B)
typedef __attribute__((ext_vector_type(4))) float float4v;   // MFMA C/D

// float -> bf16 (RNE) and back, on bit patterns
__device__ __forceinline__ unsigned short f2bf(float f) {
  unsigned u = __float_as_uint(f);
  return (unsigned short)((u + 0x7FFF + ((u >> 16) & 1)) >> 16);
}
__device__ __forceinline__ float bf2f(unsigned short h) {
  return __uint_as_float((unsigned)h << 16);
}

// ---------------------------------------------------------------------------
// fp32 GEMM (used for Wo): C[M,256] = A @ W + bias, natural layout.
// ---------------------------------------------------------------------------
__global__ __launch_bounds__(256, 2) void gemm_bias_kernel(
    const float* __restrict__ A, const float* __restrict__ W,
    const float* __restrict__ bias, float* __restrict__ C) {
  __shared__ __align__(16) float sA[32 * 68];
  __shared__ __align__(16) float sW[32 * 260];
  const int t  = threadIdx.x;
  const int tx = t & 31;
  const int ty = t >> 5;
  const size_t m0 = (size_t)blockIdx.x * 64;

  float acc[8][8] = {};

  for (int kc = 0; kc < 8; ++kc) {
    const int k0 = kc << 5;
    __syncthreads();
#pragma unroll
    for (int l = 0; l < 2; ++l) {
      const int idx = t + (l << 8);
      const int r = idx >> 3, cf = (idx & 7) << 2;
      const float4 a4 = *(const float4*)(A + (m0 + r) * 256 + k0 + cf);
      sA[(cf + 0) * 68 + r] = a4.x;
      sA[(cf + 1) * 68 + r] = a4.y;
      sA[(cf + 2) * 68 + r] = a4.z;
      sA[(cf + 3) * 68 + r] = a4.w;
    }
#pragma unroll
    for (int l = 0; l < 8; ++l) {
      const int idx = t + (l << 8);
      const int kr = idx >> 6, nc = (idx & 63) << 2;
      *(float4*)&sW[kr * 260 + nc] =
          *(const float4*)(W + (size_t)(k0 + kr) * 256 + nc);
    }
    __syncthreads();
#pragma unroll
    for (int kk = 0; kk < 32; ++kk) {
      const float4 a0 = *(const float4*)&sA[kk * 68 + (ty << 3)];
      const float4 a1 = *(const float4*)&sA[kk * 68 + (ty << 3) + 4];
      const float4 b0 = *(const float4*)&sW[kk * 260 + (tx << 2)];
      const float4 b1 = *(const float4*)&sW[kk * 260 + 128 + (tx << 2)];
      const float av[8] = {a0.x, a0.y, a0.z, a0.w, a1.x, a1.y, a1.z, a1.w};
      const float bv[8] = {b0.x, b0.y, b0.z, b0.w, b1.x, b1.y, b1.z, b1.w};
#pragma unroll
      for (int i = 0; i < 8; ++i)
#pragma unroll
        for (int c = 0; c < 8; ++c) acc[i][c] += av[i] * bv[c];
    }
  }

  const float4 bb0 = *(const float4*)(bias + (tx << 2));
  const float4 bb1 = *(const float4*)(bias + 128 + (tx << 2));
#pragma unroll
  for (int i = 0; i < 8; ++i) {
    float4 o0, o1;
    o0.x = acc[i][0] + bb0.x; o0.y = acc[i][1] + bb0.y;
    o0.z = acc[i][2] + bb0.z; o0.w = acc[i][3] + bb0.w;
    o1.x = acc[i][4] + bb1.x; o1.y = acc[i][5] + bb1.y;
    o1.z = acc[i][6] + bb1.z; o1.w = acc[i][7] + bb1.w;
    float* cp = C + (m0 + (ty << 3) + i) * 256;
    *(float4*)(cp + (tx << 2)) = o0;
    *(float4*)(cp + 128 + (tx << 2)) = o1;
  }
}

// ---------------------------------------------------------------------------
// Projection GEMM -> split-bf16 NATURAL output [b][s][d]: yh + yl (hi/lo).
// scale folded in before the split (Q uses 1/16, K uses 1).
// ---------------------------------------------------------------------------
__global__ __launch_bounds__(256, 2) void proj_split_nat_kernel(
    const float* __restrict__ A, const float* __restrict__ W,
    const float* __restrict__ bias, short* __restrict__ outh,
    short* __restrict__ outl, float scale) {
  __shared__ __align__(16) float sA[32 * 68];
  __shared__ __align__(16) float sW[32 * 260];
  const int t  = threadIdx.x;
  const int tx = t & 31;
  const int ty = t >> 5;
  const size_t m0 = (size_t)blockIdx.x * 64;

  float acc[8][8] = {};

  for (int kc = 0; kc < 8; ++kc) {
    const int k0 = kc << 5;
    __syncthreads();
#pragma unroll
    for (int l = 0; l < 2; ++l) {
      const int idx = t + (l << 8);
      const int r = idx >> 3, cf = (idx & 7) << 2;
      const float4 a4 = *(const float4*)(A + (m0 + r) * 256 + k0 + cf);
      sA[(cf + 0) * 68 + r] = a4.x;
      sA[(cf + 1) * 68 + r] = a4.y;
      sA[(cf + 2) * 68 + r] = a4.z;
      sA[(cf + 3) * 68 + r] = a4.w;
    }
#pragma unroll
    for (int l = 0; l < 8; ++l) {
      const int idx = t + (l << 8);
      const int kr = idx >> 6, nc = (idx & 63) << 2;
      *(float4*)&sW[kr * 260 + nc] =
          *(const float4*)(W + (size_t)(k0 + kr) * 256 + nc);
    }
    __syncthreads();
#pragma unroll
    for (int kk = 0; kk < 32; ++kk) {
      const float4 a0 = *(const float4*)&sA[kk * 68 + (ty << 3)];
      const float4 a1 = *(const float4*)&sA[kk * 68 + (ty << 3) + 4];
      const float4 b0 = *(const float4*)&sW[kk * 260 + (tx << 2)];
      const float4 b1 = *(const float4*)&sW[kk * 260 + 128 + (tx << 2)];
      const float av[8] = {a0.x, a0.y, a0.z, a0.w, a1.x, a1.y, a1.z, a1.w};
      const float bv[8] = {b0.x, b0.y, b0.z, b0.w, b1.x, b1.y, b1.z, b1.w};
#pragma unroll
      for (int i = 0; i < 8; ++i)
#pragma unroll
        for (int c = 0; c < 8; ++c) acc[i][c] += av[i] * bv[c];
    }
  }

  const float4 bb0 = *(const float4*)(bias + (tx << 2));
  const float4 bb1 = *(const float4*)(bias + 128 + (tx << 2));
  const float bb0v[4] = {bb0.x, bb0.y, bb0.z, bb0.w};
  const float bb1v[4] = {bb1.x, bb1.y, bb1.z, bb1.w};
#pragma unroll
  for (int i = 0; i < 8; ++i) {
    const size_t ro = (m0 + (ty << 3) + i) * 256;
    short4v h0, l0, h1, l1;
#pragma unroll
    for (int c = 0; c < 4; ++c) {
      const float y0 = (acc[i][c] + bb0v[c]) * scale;
      const unsigned short hh0 = f2bf(y0);
      h0[c] = (short)hh0; l0[c] = (short)f2bf(y0 - bf2f(hh0));
      const float y1 = (acc[i][4 + c] + bb1v[c]) * scale;
      const unsigned short hh1 = f2bf(y1);
      h1[c] = (short)hh1; l1[c] = (short)f2bf(y1 - bf2f(hh1));
    }
    *(short4v*)(outh + ro + (tx << 2)) = h0;
    *(short4v*)(outl + ro + (tx << 2)) = l0;
    *(short4v*)(outh + ro + 128 + (tx << 2)) = h1;
    *(short4v*)(outl + ro + 128 + (tx << 2)) = l1;
  }
}

// ---------------------------------------------------------------------------
// V projection -> split-bf16 TRANSPOSED output [b][d][s]: vth + vtl.
// ---------------------------------------------------------------------------
__global__ __launch_bounds__(256, 2) void proj_split_t_kernel(
    const float* __restrict__ A, const float* __restrict__ W,
    const float* __restrict__ bias, short* __restrict__ vth,
    short* __restrict__ vtl) {
  __shared__ __align__(16) float sA[32 * 68];
  __shared__ __align__(16) float sW[32 * 260];
  const int t  = threadIdx.x;
  const int tx = t & 31;
  const int ty = t >> 5;
  const size_t m0 = (size_t)blockIdx.x * 64;

  float acc[8][8] = {};

  for (int kc = 0; kc < 8; ++kc) {
    const int k0 = kc << 5;
    __syncthreads();
#pragma unroll
    for (int l = 0; l < 2; ++l) {
      const int idx = t + (l << 8);
      const int r = idx >> 3, cf = (idx & 7) << 2;
      const float4 a4 = *(const float4*)(A + (m0 + r) * 256 + k0 + cf);
      sA[(cf + 0) * 68 + r] = a4.x;
      sA[(cf + 1) * 68 + r] = a4.y;
      sA[(cf + 2) * 68 + r] = a4.z;
      sA[(cf + 3) * 68 + r] = a4.w;
    }
#pragma unroll
    for (int l = 0; l < 8; ++l) {
      const int idx = t + (l << 8);
      const int kr = idx >> 6, nc = (idx & 63) << 2;
      *(float4*)&sW[kr * 260 + nc] =
          *(const float4*)(W + (size_t)(k0 + kr) * 256 + nc);
    }
    __syncthreads();
#pragma unroll
    for (int kk = 0; kk < 32; ++kk) {
      const float4 a0 = *(const float4*)&sA[kk * 68 + (ty << 3)];
      const float4 a1 = *(const float4*)&sA[kk * 68 + (ty << 3) + 4];
      const float4 b0 = *(const float4*)&sW[kk * 260 + (tx << 2)];
      const float4 b1 = *(const float4*)&sW[kk * 260 + 128 + (tx << 2)];
      const float av[8] = {a0.x, a0.y, a0.z, a0.w, a1.x, a1.y, a1.z, a1.w};
      const float bv[8] = {b0.x, b0.y, b0.z, b0.w, b1.x, b1.y, b1.z, b1.w};
#pragma unroll
      for (int i = 0; i < 8; ++i)
#pragma unroll
        for (int c = 0; c < 8; ++c) acc[i][c] += av[i] * bv[c];
    }
  }

  const size_t bD = (size_t)(m0 >> 12) * (D_ * (size_t)S_);
  const int s0r = (int)(m0 & 4095) + (ty << 3);
#pragma unroll
  for (int c = 0; c < 8; ++c) {
    const int n = (c < 4) ? ((tx << 2) + c) : (128 + (tx << 2) + (c - 4));
    const float bn = bias[n];
    short8v h8, l8;
#pragma unroll
    for (int i = 0; i < 8; ++i) {
      const float y = acc[i][c] + bn;
      const unsigned short hh = f2bf(y);
      h8[i] = (short)hh; l8[i] = (short)f2bf(y - bf2f(hh));
    }
    *(short8v*)(vth + bD + (size_t)n * S_ + s0r) = h8;
    *(short8v*)(vtl + bD + (size_t)n * S_ + s0r) = l8;
  }
}

// ---------------------------------------------------------------------------
// MFMA flash attention, split-bf16 (3-term: Ah*Bh + Ah*Bl + Al*Bh).
// Grid (S/64, B), 256 threads = 4 waves; wave w owns q-rows q0+16w..+15.
// Q A-frags in registers (scaled 1/16 at projection). K staged natural
// [32 j][264 pad] bf16; V staged transposed [256 d][40 pad] (from vth/vtl);
// P round-trips LDS packed (ph<<16|pl) in C-layout -> A-layout.
// All LDS frag patterns hit the 8 bank-quads uniformly (conflict-free).
// ---------------------------------------------------------------------------
__global__ __launch_bounds__(256, 1) void flash_attn_mfma(
    const short* __restrict__ qh, const short* __restrict__ ql,
    const short* __restrict__ kh, const short* __restrict__ kl,
    const short* __restrict__ vth, const short* __restrict__ vtl,
    float* __restrict__ ctx) {
  // union buffer: K-phase Kh[32*264]@0, Kl@8448 | V-phase Vth[256*40]@0, Vtl@10240
  __shared__ __align__(16) short sKV[20480];   // 40 KB
  __shared__ unsigned int sP[4][16][36];       // 9 KB, per-wave P tiles

  const int t    = threadIdx.x;
  const int w    = t >> 6;
  const int lane = t & 63;
  const int m    = lane & 15;
  const int quad = lane >> 4;
  const int q0   = blockIdx.x * 64;
  const int b    = blockIdx.y;
  const size_t sd = (size_t)b * (S_ * (size_t)D_);

  // Q A-frags, resident in registers for the whole kernel
  short8v aqh[8], aql[8];
  {
    const size_t row = sd + (size_t)(q0 + 16 * w + m) * D_;
#pragma unroll
    for (int kk = 0; kk < 8; ++kk) {
      const size_t off = row + kk * 32 + quad * 8;
      aqh[kk] = *(const short8v*)(qh + off);
      aql[kk] = *(const short8v*)(ql + off);
    }
  }

  float4v acc[16];
#pragma unroll
  for (int dt = 0; dt < 16; ++dt) acc[dt] = (float4v){0.f, 0.f, 0.f, 0.f};
  float m_i[4], l_i[4];
#pragma unroll
  for (int r = 0; r < 4; ++r) { m_i[r] = -INFINITY; l_i[r] = 0.f; }

  for (int jt = 0; jt < 128; ++jt) {
    const int j0 = jt << 5;

    __syncthreads();  // prior PV reads of sKV done
    // ---- stage Kh, Kl: [32 j][256 d] -> rows padded to 264 ----
#pragma unroll
    for (int l = 0; l < 4; ++l) {
      const int idx = t + (l << 8);          // 0..1023 chunks of 8 shorts
      const int r = idx >> 5;                // j-row 0..31
      const int cc = (idx & 31) << 3;        // d-col 0..255 step 8
      const size_t g = sd + (size_t)(j0 + r) * D_ + cc;
      *(short8v*)&sKV[r * 264 + cc]        = *(const short8v*)(kh + g);
      *(short8v*)&sKV[8448 + r * 264 + cc] = *(const short8v*)(kl + g);
    }
    __syncthreads();

    // ---- scores: 16(q) x 32(j), D in 8 K-steps of 32 ----
    float4v s0 = (float4v){0.f, 0.f, 0.f, 0.f};
    float4v s1 = (float4v){0.f, 0.f, 0.f, 0.f};
#pragma unroll
    for (int kk = 0; kk < 8; ++kk) {
      const int co = kk * 32 + quad * 8;
      const short8v bh0 = *(const short8v*)&sKV[m * 264 + co];
      const short8v bl0 = *(const short8v*)&sKV[8448 + m * 264 + co];
      const short8v bh1 = *(const short8v*)&sKV[(16 + m) * 264 + co];
      const short8v bl1 = *(const short8v*)&sKV[8448 + (16 + m) * 264 + co];
      s0 = __builtin_amdgcn_mfma_f32_16x16x32_bf16(aqh[kk], bh0, s0, 0, 0, 0);
      s0 = __builtin_amdgcn_mfma_f32_16x16x32_bf16(aqh[kk], bl0, s0, 0, 0, 0);
      s0 = __builtin_amdgcn_mfma_f32_16x16x32_bf16(aql[kk], bh0, s0, 0, 0, 0);
      s1 = __builtin_amdgcn_mfma_f32_16x16x32_bf16(aqh[kk], bh1, s1, 0, 0, 0);
      s1 = __builtin_amdgcn_mfma_f32_16x16x32_bf16(aqh[kk], bl1, s1, 0, 0, 0);
      s1 = __builtin_amdgcn_mfma_f32_16x16x32_bf16(aql[kk], bh1, s1, 0, 0, 0);
    }

    // ---- online softmax (row r of this wave's tile = quad*4 + r) ----
    float alpha[4], pr0[4], pr1[4];
#pragma unroll
    for (int r = 0; r < 4; ++r) {
      float mx = fmaxf(s0[r], s1[r]);
      mx = fmaxf(mx, __shfl_xor(mx, 1, 64));
      mx = fmaxf(mx, __shfl_xor(mx, 2, 64));
      mx = fmaxf(mx, __shfl_xor(mx, 4, 64));
      mx = fmaxf(mx, __shfl_xor(mx, 8, 64));
      const float mnew = fmaxf(m_i[r], mx);
      alpha[r] = __expf(m_i[r] - mnew);
      m_i[r] = mnew;
      const float p0 = __expf(s0[r] - mnew);
      const float p1 = __expf(s1[r] - mnew);
      float rs = p0 + p1;
      rs += __shfl_xor(rs, 1, 64);
      rs += __shfl_xor(rs, 2, 64);
      rs += __shfl_xor(rs, 4, 64);
      rs += __shfl_xor(rs, 8, 64);
      l_i[r] = l_i[r] * alpha[r] + rs;
      pr0[r] = p0; pr1[r] = p1;
    }

    // ---- write split P to per-wave LDS (C-layout -> [row][j] packed) ----
#pragma unroll
    for (int r = 0; r < 4; ++r) {
      {
        const float p = pr0[r];
        const unsigned short hh = f2bf(p);
        const unsigned short ll = f2bf(p - bf2f(hh));
        sP[w][quad * 4 + r][m] = ((unsigned)hh << 16) | (unsigned)ll;
      }
      {
        const float p = pr1[r];
        const unsigned short hh = f2bf(p);
        const unsigned short ll = f2bf(p - bf2f(hh));
        sP[w][quad * 4 + r][16 + m] = ((unsigned)hh << 16) | (unsigned)ll;
      }
    }

    // ---- rescale ctx accumulators ----
#pragma unroll
    for (int dt = 0; dt < 16; ++dt)
#pragma unroll
      for (int r = 0; r < 4; ++r) acc[dt][r] *= alpha[r];

    __syncthreads();  // all waves done reading K tile
    // ---- stage Vth, Vtl: [256 d][32 j] -> rows padded to 40 ----
    {
      const size_t g = (size_t)b * (D_ * (size_t)S_) + (size_t)t * S_ + j0;
#pragma unroll
      for (int l = 0; l < 4; ++l) {
        *(short8v*)&sKV[t * 40 + (l << 3)]         = *(const short8v*)(vth + g + (l << 3));
        *(short8v*)&sKV[10240 + t * 40 + (l << 3)] = *(const short8v*)(vtl + g + (l << 3));
      }
    }
    __syncthreads();

    // ---- P A-frag: read back in A-layout, unpack hi/lo ----
    short8v ph, pl;
    {
      const uint4 pa = *(const uint4*)&sP[w][m][quad * 8];
      const uint4 pb = *(const uint4*)&sP[w][m][quad * 8 + 4];
      ph[0] = (short)(pa.x >> 16); pl[0] = (short)(pa.x & 0xffff);
      ph[1] = (short)(pa.y >> 16); pl[1] = (short)(pa.y & 0xffff);
      ph[2] = (short)(pa.z >> 16); pl[2] = (short)(pa.z & 0xffff);
      ph[3] = (short)(pa.w >> 16); pl[3] = (short)(pa.w & 0xffff);
      ph[4] = (short)(pb.x >> 16); pl[4] = (short)(pb.x & 0xffff);
      ph[5] = (short)(pb.y >> 16); pl[5] = (short)(pb.y & 0xffff);
      ph[6] = (short)(pb.z >> 16); pl[6] = (short)(pb.z & 0xffff);
      ph[7] = (short)(pb.w >> 16); pl[7] = (short)(pb.w & 0xffff);
    }

    // ---- PV: ctx[16 q][256 d] += P[16 q][32 j] @ V[32 j][256 d] ----
#pragma unroll
    for (int dt = 0; dt < 16; ++dt) {
      const int vr = (dt * 16 + m) * 40 + quad * 8;
      const short8v bh = *(const short8v*)&sKV[vr];
      const short8v bl = *(const short8v*)&sKV[10240 + vr];
      acc[dt] = __builtin_amdgcn_mfma_f32_16x16x32_bf16(ph, bh, acc[dt], 0, 0, 0);
      acc[dt] = __builtin_amdgcn_mfma_f32_16x16x32_bf16(ph, bl, acc[dt], 0, 0, 0);
      acc[dt] = __builtin_amdgcn_mfma_f32_16x16x32_bf16(pl, bh, acc[dt], 0, 0, 0);
    }
  }

  // ---- finalize: divide by l, store ctx (C-layout scatter, 64B granules) ----
#pragma unroll
  for (int r = 0; r < 4; ++r) {
    const float inv = 1.0f / l_i[r];
    float* cp = ctx + sd + (size_t)(q0 + 16 * w + quad * 4 + r) * D_ + m;
#pragma unroll
    for (int dt = 0; dt < 16; ++dt) cp[dt * 16] = acc[dt][r] * inv;
  }
}

// ---------------------------------------------------------------------------
// w[row] = dot(logits[row,:], cv)
// ---------------------------------------------------------------------------
__global__ __launch_bounds__(256) void wdot_kernel(
    const float* __restrict__ logits, const float* __restrict__ cv,
    float* __restrict__ w) {
  const int t    = threadIdx.x;
  const int wave = t >> 6, lane = t & 63;
  const size_t row = (size_t)blockIdx.x * 4 + wave;
  const float4 l4 = *(const float4*)(logits + row * 256 + (lane << 2));
  const float4 c4 = *(const float4*)(cv + (lane << 2));
  float p = l4.x * c4.x + l4.y * c4.y + l4.z * c4.z + l4.w * c4.w;
#pragma unroll
  for (int off = 32; off > 0; off >>= 1) p += __shfl_down(p, off, 64);
  if (lane == 0) w[row] = p;
}

// ---------------------------------------------------------------------------
// softmax over sequence dim per batch (in place on w)
// ---------------------------------------------------------------------------
__global__ __launch_bounds__(256) void seq_softmax_kernel(float* __restrict__ w) {
  __shared__ float red[4];
  const int b = blockIdx.x, t = threadIdx.x;
  const int wave = t >> 6, lane = t & 63;
  float* wb = w + (size_t)b * S_;
  float vals[16];
  float mx = -INFINITY;
#pragma unroll
  for (int i = 0; i < 16; ++i) {
    vals[i] = wb[t + (i << 8)];
    mx = fmaxf(mx, vals[i]);
  }
#pragma unroll
  for (int off = 32; off > 0; off >>= 1) mx = fmaxf(mx, __shfl_xor(mx, off, 64));
  if (lane == 0) red[wave] = mx;
  __syncthreads();
  const float M = fmaxf(fmaxf(red[0], red[1]), fmaxf(red[2], red[3]));
  float sum = 0.f;
#pragma unroll
  for (int i = 0; i < 16; ++i) {
    vals[i] = __expf(vals[i] - M);
    sum += vals[i];
  }
#pragma unroll
  for (int off = 32; off > 0; off >>= 1) sum += __shfl_xor(sum, off, 64);
  __syncthreads();
  if (lane == 0) red[wave] = sum;
  __syncthreads();
  const float inv = 1.0f / (red[0] + red[1] + red[2] + red[3]);
#pragma unroll
  for (int i = 0; i < 16; ++i) wb[t + (i << 8)] = vals[i] * inv;
}

// ---------------------------------------------------------------------------
// out[b,s,:] *= nw[b,s]
// ---------------------------------------------------------------------------
__global__ __launch_bounds__(256) void scale_kernel(
    float* __restrict__ out, const float* __restrict__ nw) {
  const size_t g = (size_t)blockIdx.x * 256 + threadIdx.x;
  float4* o4 = (float4*)out;
  float4 vv = o4[g];
  const float sc = nw[g >> 6];
  vv.x *= sc; vv.y *= sc; vv.z *= sc; vv.w *= sc;
  o4[g] = vv;
}

// ---------------------------------------------------------------------------
extern "C" void kernel_launch(void* const* d_in, const int* in_sizes, int n_in,
                              void* d_out, int out_size, void* d_ws, size_t ws_size,
                              hipStream_t stream) {
  const float* x  = (const float*)d_in[0];
  const float* Wq = (const float*)d_in[1];
  const float* bq = (const float*)d_in[2];
  const float* Wk = (const float*)d_in[3];
  const float* bk = (const float*)d_in[4];
  const float* Wv = (const float*)d_in[5];
  const float* bv = (const float*)d_in[6];
  const float* Wo = (const float*)d_in[7];
  const float* bo = (const float*)d_in[8];
  const float* cv = (const float*)d_in[9];
  float* out = (float*)d_out;

  const size_t N = (size_t)B_ * S_ * D_;  // 8,388,608 elements
  short* qh  = (short*)d_ws;      // [b][s][d] bf16 hi (Q pre-scaled by 1/16)
  short* ql  = qh + N;            // [b][s][d] bf16 lo
  short* kh  = ql + N;            // [b][s][d]
  short* kl  = kh + N;
  short* vth = kl + N;            // [b][d][s]
  short* vtl = vth + N;
  float* ctx = (float*)(vtl + N); // [b][s][d] fp32
  float* w   = ctx + N;           // B*S floats

  proj_split_nat_kernel<<<512, 256, 0, stream>>>(x, Wq, bq, qh, ql, 0.0625f);
  proj_split_nat_kernel<<<512, 256, 0, stream>>>(x, Wk, bk, kh, kl, 1.0f);
  proj_split_t_kernel<<<512, 256, 0, stream>>>(x, Wv, bv, vth, vtl);
  flash_attn_mfma<<<dim3(64, 8), 256, 0, stream>>>(qh, ql, kh, kl, vth, vtl, ctx);
  gemm_bias_kernel<<<512, 256, 0, stream>>>(ctx, Wo, bo, out);
  wdot_kernel<<<8192, 256, 0, stream>>>(out, cv, w);
  seq_softmax_kernel<<<8, 256, 0, stream>>>(w);
  scale_kernel<<<8192, 256, 0, stream>>>(out, w);
}